// Round 1
// baseline (128.434 us; speedup 1.0000x reference)
//
#include <hip/hip_runtime.h>
#include <hip/hip_bf16.h>
#include <stdint.h>

// Problem constants: B=2, T=2048, D=1024, H=16, W=256, HD=64
// M = B*T = 4096 rows.

typedef __attribute__((ext_vector_type(8))) short short8;
typedef __attribute__((ext_vector_type(4))) float f32x4;

#define MFMA16(a, b, c) __builtin_amdgcn_mfma_f32_16x16x32_bf16((a), (b), (c), 0, 0, 0)

static __device__ __forceinline__ void gl_lds16(const void* g, void* l) {
  __builtin_amdgcn_global_load_lds(
      (const __attribute__((address_space(1))) unsigned int*)g,
      (__attribute__((address_space(3))) unsigned int*)l, 16, 0, 0);
}

// ---------------------------------------------------------------- convert
__global__ void cvt_bf16(const float* __restrict__ in,
                         __hip_bfloat16* __restrict__ out, int n8) {
  int i = blockIdx.x * blockDim.x + threadIdx.x;
  int stride = gridDim.x * blockDim.x;
  for (; i < n8; i += stride) {
    const float4* p = (const float4*)in + (size_t)i * 2;
    float4 v0 = p[0], v1 = p[1];
    union { short8 s; __hip_bfloat16 h[8]; } u;
    u.h[0] = __float2bfloat16(v0.x); u.h[1] = __float2bfloat16(v0.y);
    u.h[2] = __float2bfloat16(v0.z); u.h[3] = __float2bfloat16(v0.w);
    u.h[4] = __float2bfloat16(v1.x); u.h[5] = __float2bfloat16(v1.y);
    u.h[6] = __float2bfloat16(v1.z); u.h[7] = __float2bfloat16(v1.w);
    ((short8*)out)[i] = u.s;
  }
}

// ---------------------------------------------------------------- GEMM (B^T)
// C[m][n] = sum_k A[m][k] * Bm[n][k] + bias[n]
// MODE 0: QKV epilogue (scatter to q/k/v buffers, q scaled by 1/8)
// MODE 1: plain fp32 output
template <int MODE>
__global__ __launch_bounds__(256) void gemm_bt(
    const __hip_bfloat16* __restrict__ A, const __hip_bfloat16* __restrict__ Bm,
    const float* __restrict__ bias, float* __restrict__ outF,
    __hip_bfloat16* __restrict__ qb, __hip_bfloat16* __restrict__ kb,
    __hip_bfloat16* __restrict__ vt, int K, int nbn) {
  __shared__ alignas(16) __hip_bfloat16 As[128 * 32];
  __shared__ alignas(16) __hip_bfloat16 Bs[128 * 32];
  const int bm = blockIdx.x / nbn, bn = blockIdx.x % nbn;
  const int tid = threadIdx.x;
  const int lane = tid & 63, w = tid >> 6;
  const int wr = w >> 1, wc = w & 1;
  const int r = lane & 15, g = lane >> 4;

  f32x4 acc[4][4] = {};

  const int c0 = tid, c1 = tid + 256;
  const __hip_bfloat16* a0 = A + (size_t)(bm * 128 + (c0 >> 2)) * K + (c0 & 3) * 8;
  const __hip_bfloat16* a1 = A + (size_t)(bm * 128 + (c1 >> 2)) * K + (c1 & 3) * 8;
  const __hip_bfloat16* b0 = Bm + (size_t)(bn * 128 + (c0 >> 2)) * K + (c0 & 3) * 8;
  const __hip_bfloat16* b1 = Bm + (size_t)(bn * 128 + (c1 >> 2)) * K + (c1 & 3) * 8;
  __hip_bfloat16* la0 = &As[c0 * 8];
  __hip_bfloat16* la1 = &As[c1 * 8];
  __hip_bfloat16* lb0 = &Bs[c0 * 8];
  __hip_bfloat16* lb1 = &Bs[c1 * 8];

  for (int k0 = 0; k0 < K; k0 += 32) {
    gl_lds16(a0 + k0, la0);
    gl_lds16(a1 + k0, la1);
    gl_lds16(b0 + k0, lb0);
    gl_lds16(b1 + k0, lb1);
    __syncthreads();
    short8 af[4], bf[4];
#pragma unroll
    for (int i = 0; i < 4; ++i)
      af[i] = *(const short8*)&As[(wr * 64 + i * 16 + r) * 32 + g * 8];
#pragma unroll
    for (int j = 0; j < 4; ++j)
      bf[j] = *(const short8*)&Bs[(wc * 64 + j * 16 + r) * 32 + g * 8];
#pragma unroll
    for (int i = 0; i < 4; ++i)
#pragma unroll
      for (int j = 0; j < 4; ++j) acc[i][j] = MFMA16(af[i], bf[j], acc[i][j]);
    __syncthreads();
  }

#pragma unroll
  for (int i = 0; i < 4; ++i) {
    const int mbase = bm * 128 + wr * 64 + i * 16 + g * 4;
#pragma unroll
    for (int j = 0; j < 4; ++j) {
      const int nn = bn * 128 + wc * 64 + j * 16 + r;
      const float bv = bias[nn];
      if (MODE == 1) {
#pragma unroll
        for (int q = 0; q < 4; ++q)
          outF[(size_t)(mbase + q) * 1024 + nn] = acc[i][j][q] + bv;
      } else {
        const int c = nn >> 10, h = (nn >> 6) & 15, hd = nn & 63;
#pragma unroll
        for (int q = 0; q < 4; ++q) {
          const int m = mbase + q;
          const int b_ = m >> 11, t = m & 2047;
          const float v = acc[i][j][q] + bv;
          if (c == 0)
            qb[((size_t)((b_ * 16 + h) * 2048 + t) << 6) + hd] =
                __float2bfloat16(v * 0.125f);
          else if (c == 1)
            kb[((size_t)((b_ * 16 + h) * 2048 + t) << 6) + hd] =
                __float2bfloat16(v);
          else
            vt[(size_t)((b_ * 16 + h) * 64 + hd) * 2048 + t] =
                __float2bfloat16(v);
        }
      }
    }
  }
}

// ---------------------------------------------------------------- attention
// One block per (b*16+h, q-tile of 64). 4 waves; wave w owns 16 query rows.
// Flash-style over 32-key blocks within the causal band [i-255, i].
__global__ __launch_bounds__(256) void attn_local(
    const __hip_bfloat16* __restrict__ qb, const __hip_bfloat16* __restrict__ kb,
    const __hip_bfloat16* __restrict__ vt, __hip_bfloat16* __restrict__ yb) {
  __shared__ alignas(16) __hip_bfloat16 plds[4][16 * 32];
  const int bh = blockIdx.x >> 5;  // b*16 + h
  const int qt = blockIdx.x & 31;
  const int w = threadIdx.x >> 6, lane = threadIdx.x & 63;
  const int r = lane & 15, g = lane >> 4;
  const int qa = qt * 64 + w * 16;

  const __hip_bfloat16* qp = qb + (size_t)bh * 2048 * 64;
  const __hip_bfloat16* kp = kb + (size_t)bh * 2048 * 64;
  const __hip_bfloat16* vp = vt + (size_t)bh * 64 * 2048;

  const short8 qf0 = *(const short8*)&qp[(qa + r) * 64 + g * 8];
  const short8 qf1 = *(const short8*)&qp[(qa + r) * 64 + g * 8 + 32];

  f32x4 acc[4] = {};
  float mrow[4] = {-1e30f, -1e30f, -1e30f, -1e30f};
  float lrow[4] = {0.f, 0.f, 0.f, 0.f};

  const int jmin = qa > 255 ? qa - 255 : 0;
  const int kb_lo = jmin >> 5;
  const int kb_hi = (qa + 15) >> 5;

  for (int kbi = kb_lo; kbi <= kb_hi; ++kbi) {
    const int kbase = kbi << 5;
    f32x4 s[2] = {};
#pragma unroll
    for (int f = 0; f < 2; ++f) {
      short8 kf0 = *(const short8*)&kp[(kbase + f * 16 + r) * 64 + g * 8];
      short8 kf1 = *(const short8*)&kp[(kbase + f * 16 + r) * 64 + g * 8 + 32];
      s[f] = MFMA16(qf0, kf0, s[f]);
      s[f] = MFMA16(qf1, kf1, s[f]);
    }
    bool valid[2][4];
    float sv[2][4];
#pragma unroll
    for (int f = 0; f < 2; ++f)
#pragma unroll
      for (int q = 0; q < 4; ++q) {
        const int i_ = qa + g * 4 + q;
        const int j_ = kbase + f * 16 + r;
        valid[f][q] = (j_ <= i_) && (j_ + 255 >= i_);
        sv[f][q] = valid[f][q] ? s[f][q] : -1e30f;
      }
    float rm[4];
#pragma unroll
    for (int q = 0; q < 4; ++q) rm[q] = fmaxf(sv[0][q], sv[1][q]);
#pragma unroll
    for (int d = 1; d < 16; d <<= 1)
#pragma unroll
      for (int q = 0; q < 4; ++q) rm[q] = fmaxf(rm[q], __shfl_xor(rm[q], d));
    float p[2][4], rs[4];
#pragma unroll
    for (int q = 0; q < 4; ++q) {
      const float mnew = fmaxf(mrow[q], rm[q]);
      const float fac = __expf(mrow[q] - mnew);
      mrow[q] = mnew;
      lrow[q] *= fac;
#pragma unroll
      for (int hdb = 0; hdb < 4; ++hdb) acc[hdb][q] *= fac;
      p[0][q] = valid[0][q] ? __expf(sv[0][q] - mnew) : 0.f;
      p[1][q] = valid[1][q] ? __expf(sv[1][q] - mnew) : 0.f;
      rs[q] = p[0][q] + p[1][q];
    }
#pragma unroll
    for (int d = 1; d < 16; d <<= 1)
#pragma unroll
      for (int q = 0; q < 4; ++q) rs[q] += __shfl_xor(rs[q], d);
#pragma unroll
    for (int q = 0; q < 4; ++q) lrow[q] += rs[q];
    // P: C-layout -> LDS -> A-layout (wave-private region, no block barrier)
#pragma unroll
    for (int f = 0; f < 2; ++f)
#pragma unroll
      for (int q = 0; q < 4; ++q)
        plds[w][(g * 4 + q) * 32 + f * 16 + r] = __float2bfloat16(p[f][q]);
    asm volatile("s_waitcnt lgkmcnt(0)" ::: "memory");
    __builtin_amdgcn_sched_barrier(0);
    const short8 pa = *(const short8*)&plds[w][r * 32 + g * 8];
#pragma unroll
    for (int hdb = 0; hdb < 4; ++hdb) {
      short8 vf = *(const short8*)&vp[(size_t)(hdb * 16 + r) * 2048 + kbase + g * 8];
      acc[hdb] = MFMA16(pa, vf, acc[hdb]);
    }
  }

  const int b_ = bh >> 4, h = bh & 15;
#pragma unroll
  for (int hdb = 0; hdb < 4; ++hdb)
#pragma unroll
    for (int q = 0; q < 4; ++q) {
      const int i_ = qa + g * 4 + q;
      yb[(size_t)(b_ * 2048 + i_) * 1024 + h * 64 + hdb * 16 + r] =
          __float2bfloat16(acc[hdb][q] / lrow[q]);
    }
}

// ---------------------------------------------------------------- launch
extern "C" void kernel_launch(void* const* d_in, const int* in_sizes, int n_in,
                              void* d_out, int out_size, void* d_ws,
                              size_t ws_size, hipStream_t stream) {
  const float* x = (const float*)d_in[0];
  const float* Wqkv = (const float*)d_in[1];
  const float* bqkv = (const float*)d_in[2];
  const float* Wo = (const float*)d_in[3];
  const float* bo = (const float*)d_in[4];
  float* out = (float*)d_out;

  char* ws = (char*)d_ws;
  __hip_bfloat16* xb = (__hip_bfloat16*)(ws + 0);                    // 8 MB
  __hip_bfloat16* wqkvb = (__hip_bfloat16*)(ws + 8388608);           // 6 MB
  __hip_bfloat16* wob = (__hip_bfloat16*)(ws + 14680064);            // 2 MB
  __hip_bfloat16* qb = (__hip_bfloat16*)(ws + 16777216);             // 8 MB
  __hip_bfloat16* kb = (__hip_bfloat16*)(ws + 25165824);             // 8 MB
  __hip_bfloat16* vt = (__hip_bfloat16*)(ws + 33554432);             // 8 MB
  __hip_bfloat16* yb = (__hip_bfloat16*)(ws + 41943040);             // 8 MB

  cvt_bf16<<<2048, 256, 0, stream>>>(x, xb, 4194304 / 8);
  cvt_bf16<<<1536, 256, 0, stream>>>(Wqkv, wqkvb, 3145728 / 8);
  cvt_bf16<<<512, 256, 0, stream>>>(Wo, wob, 1048576 / 8);

  // QKV: M=4096, N=3072, K=1024
  gemm_bt<0><<<32 * 24, 256, 0, stream>>>(xb, wqkvb, bqkv, nullptr, qb, kb, vt,
                                          1024, 24);
  // attention: blocks = (B*H) * (T/64) = 32 * 32
  attn_local<<<1024, 256, 0, stream>>>(qb, kb, vt, yb);
  // out: M=4096, N=1024, K=1024
  gemm_bt<1><<<32 * 8, 256, 0, stream>>>(yb, wob, bo, out, nullptr, nullptr,
                                         nullptr, 1024, 8);
}